// Round 10
// baseline (451.000 us; speedup 1.0000x reference)
//
#include <hip/hip_runtime.h>

// ---------------------------------------------------------------------------
// Transformer block on MI355X. fp32 I/O (per reference), bf16 MFMA internals.
// R10: flash split into 2 dispatches (profiling visibility + same work);
// attn-combine fused into proj GEMM A-staging (combine kernel deleted);
// FC2 = BN=128 + split-K x2 with fused epilogue (x1 + S0 + S1 + bias).
// ws layout (72 MB preferred / 56 MB fallback):
//   [0,16M)   x1    f32 4096x1024
//   [16,24M)  hbuf/h2 bf16 LN out | flash: Op split0 (bf16) | FC2: S0 lo (f32)
//   [24,32M)  wT1   bf16 w_k^T / w_fc1^T | flash: Op split1 | FC2: S0 hi
//   [32,40M)  wT2   bf16 w_fc2^T | flash: lpart (512KB)
//   [40,48M)  kh    bf16 [B*H][L][64] | after flash: w_proj^T, then fc1o
//   [48,56M)  khT   bf16 [B*H][64][L] | after proj: fc1o
//   [40,72M)  fc1o  bf16 4096x4096 (unchunked path)
// d_out: FC2 split-1 fp32 partial, then final output via fuse kernel.
// ---------------------------------------------------------------------------

typedef __attribute__((ext_vector_type(8))) short s8v;  // 8 bf16 raw
typedef __attribute__((ext_vector_type(4))) short s4v;  // 4 bf16 raw
typedef __attribute__((ext_vector_type(4))) float f4v;  // mfma accumulator

#define D_MODEL 1024
#define SEQ 2048
#define BATCH 2
#define NH 16
#define DH 64
#define MROWS (BATCH * SEQ)

__device__ __forceinline__ float b2f(unsigned short u) {
  union { unsigned int i; float f; } v; v.i = ((unsigned int)u) << 16; return v.f;
}
__device__ __forceinline__ unsigned short f2b(float f) {
  unsigned int i = __builtin_bit_cast(unsigned int, f);
  unsigned int r = (i + 0x7fffu + ((i >> 16) & 1u)) >> 16;  // RNE
  return (unsigned short)r;
}
// async global->LDS, 16B/lane; dest = wave-uniform base + lane*16 (m104/m108)
__device__ __forceinline__ void async16(const void* g, void* l) {
  __builtin_amdgcn_global_load_lds(
      (const __attribute__((address_space(1))) unsigned int*)g,
      (__attribute__((address_space(3))) unsigned int*)l, 16, 0, 0);
}
__device__ __forceinline__ unsigned short cvt_b(float f) { return f2b(f); }
__device__ __forceinline__ unsigned short cvt_b(unsigned short u) { return u; }

// K=16 bf16 mfma: prefer native; fall back to zero-padded K=32.
#if __has_builtin(__builtin_amdgcn_mfma_f32_16x16x16_bf16)
__device__ __forceinline__ f4v mfma16(s4v a, s4v b, f4v c) {
  return __builtin_amdgcn_mfma_f32_16x16x16_bf16(a, b, c, 0, 0, 0);
}
#elif __has_builtin(__builtin_amdgcn_mfma_f32_16x16x16bf16_1k)
__device__ __forceinline__ f4v mfma16(s4v a, s4v b, f4v c) {
  return __builtin_amdgcn_mfma_f32_16x16x16bf16_1k(a, b, c, 0, 0, 0);
}
#else
__device__ __forceinline__ f4v mfma16(s4v a, s4v b, f4v c) {
  s8v aa = {a[0], a[1], a[2], a[3], 0, 0, 0, 0};
  s8v bb = {b[0], b[1], b[2], b[3], 0, 0, 0, 0};
  return __builtin_amdgcn_mfma_f32_16x16x32_bf16(aa, bb, c, 0, 0, 0);
}
#endif

// ---------------- LayerNorm: fp32 in -> bf16 out, one block per row ---------
__global__ __launch_bounds__(256) void ln_kernel(
    const float* __restrict__ x, const float* __restrict__ g,
    const float* __restrict__ bb, unsigned short* __restrict__ out) {
  int row = blockIdx.x;
  int t = threadIdx.x;
  const float* xr = x + (size_t)row * D_MODEL;
  float v[4];
  float s = 0.f, s2 = 0.f;
#pragma unroll
  for (int i = 0; i < 4; ++i) {
    float f = xr[t + 256 * i];
    v[i] = f; s += f; s2 += f * f;
  }
#pragma unroll
  for (int off = 1; off < 64; off <<= 1) {
    s += __shfl_xor(s, off, 64);
    s2 += __shfl_xor(s2, off, 64);
  }
  __shared__ float red[8];
  if ((t & 63) == 0) { red[t >> 6] = s; red[4 + (t >> 6)] = s2; }
  __syncthreads();
  s = red[0] + red[1] + red[2] + red[3];
  s2 = red[4] + red[5] + red[6] + red[7];
  float mu = s * (1.f / D_MODEL);
  float var = s2 * (1.f / D_MODEL) - mu * mu;
  float rstd = rsqrtf(var + 1e-5f);
#pragma unroll
  for (int i = 0; i < 4; ++i) {
    int c = t + 256 * i;
    float h = (v[i] - mu) * rstd * g[c] + bb[c];
    out[(size_t)row * D_MODEL + c] = f2b(h);
  }
}

// ---------------- batched 64x64 tile transpose -> bf16 ----------------------
template <typename T>
__global__ __launch_bounds__(256) void transpose_b(
    const T* __restrict__ src, unsigned short* __restrict__ dst,
    int srcStride, int dstStride, long long srcBatch, long long dstBatch) {
  __shared__ unsigned short tile[64][65];
  const T* s = src + (size_t)blockIdx.z * srcBatch;
  unsigned short* d = dst + (size_t)blockIdx.z * dstBatch;
  int n0 = blockIdx.x * 64, k0 = blockIdx.y * 64;
  for (int i = threadIdx.x; i < 4096; i += 256) {
    int k = i >> 6, n = i & 63;
    tile[k][n] = cvt_b(s[(size_t)(k0 + k) * srcStride + n0 + n]);
  }
  __syncthreads();
  for (int i = threadIdx.x; i < 4096; i += 256) {
    int n = i >> 6, k = i & 63;
    d[(size_t)(n0 + n) * dstStride + k0 + k] = tile[k][n];
  }
}

// ---------------- GEMM: C[M,N] = A[M,K] @ Bt[N,K]^T (+bias)(+res)(+relu) ----
// 128xBN tile, BK=64, 4 waves (2x2). lda/ldb allow split-K column windows.
template <int RES, bool RELU, bool KH, int OUTF, int BN, bool HASB>
__global__ __launch_bounds__(256) void gemm_bt(
    const unsigned short* __restrict__ A, const unsigned short* __restrict__ Bt,
    const float* __restrict__ bias, const float* __restrict__ res,
    void* __restrict__ out, int M, int N, int K, int lda, int ldb) {
  constexpr int NT = BN / 32;
  __shared__ __align__(16) unsigned short lsA[128 * 64];
  __shared__ __align__(16) unsigned short lsB[BN * 64];
  int tid = threadIdx.x;
  int lane = tid & 63, w = tid >> 6, quad = lane >> 4, l16 = lane & 15;
  int m0 = blockIdx.y * 128, n0 = blockIdx.x * BN;
  int wm = (w >> 1) * 64, wn = (w & 1) * (BN / 2);
  f4v acc[4][NT] = {};
  for (int kt = 0; kt < K; kt += 64) {
#pragma unroll
    for (int i = 0; i < 4; ++i) {
      int cb = w * 256 + i * 64;
      int ci = cb + lane;
      int row = ci >> 3, c = ci & 7;
      int cs = c ^ (row & 7);
      async16(A + (size_t)(m0 + row) * lda + kt + cs * 8, &lsA[cb * 8]);
    }
#pragma unroll
    for (int i = 0; i < BN / 32; ++i) {
      int cb = w * (BN * 2) + i * 64;
      int ci = cb + lane;
      int row = ci >> 3, c = ci & 7;
      int cs = c ^ (row & 7);
      async16(Bt + (size_t)(n0 + row) * ldb + kt + cs * 8, &lsB[cb * 8]);
    }
    __builtin_amdgcn_s_waitcnt(0x0f70);  // vmcnt(0)
    __syncthreads();
#pragma unroll
    for (int s = 0; s < 2; ++s) {
      s8v af[4], bf[NT];
#pragma unroll
      for (int t = 0; t < 4; ++t) {
        int am = wm + t * 16 + l16;
        int ac = (s * 4 + quad) ^ (am & 7);
        af[t] = *(const s8v*)(&lsA[am * 64 + ac * 8]);
      }
#pragma unroll
      for (int t = 0; t < NT; ++t) {
        int bn = wn + t * 16 + l16;
        int bc = (s * 4 + quad) ^ (bn & 7);
        bf[t] = *(const s8v*)(&lsB[bn * 64 + bc * 8]);
      }
#pragma unroll
      for (int ti = 0; ti < 4; ++ti)
#pragma unroll
        for (int tj = 0; tj < NT; ++tj)
          acc[ti][tj] = __builtin_amdgcn_mfma_f32_16x16x32_bf16(
              af[ti], bf[tj], acc[ti][tj], 0, 0, 0);
    }
    __syncthreads();
  }
#pragma unroll
  for (int tj = 0; tj < NT; ++tj) {
    int col = n0 + wn + tj * 16 + l16;
    float bv = HASB ? bias[col] : 0.f;
#pragma unroll
    for (int ti = 0; ti < 4; ++ti) {
#pragma unroll
      for (int r = 0; r < 4; ++r) {
        int rowg = m0 + wm + ti * 16 + quad * 4 + r;
        float vv = acc[ti][tj][r] + bv;
        if (RES == 2) vv += res[(size_t)rowg * N + col];
        if (RELU) vv = fmaxf(vv, 0.f);
        size_t oidx;
        if (KH) {
          int b = rowg >> 11, l = rowg & 2047, h = col >> 6, d = col & 63;
          oidx = (((size_t)(b * NH + h)) * SEQ + l) * DH + d;
        } else {
          oidx = (size_t)rowg * N + col;
        }
        if (OUTF == 0) ((unsigned short*)out)[oidx] = f2b(vv);
        else           ((float*)out)[oidx] = vv;
      }
    }
  }
}

// ---------------- proj GEMM with fused attn-combine on A --------------------
// A[row][col] = (Op0 + Op1)[row][col] / (l0+l1)[head(col)][row]; B = w_proj^T.
// x1 = A @ B + b_proj + x.  BN=64, register A-staging (combine) + async B.
__global__ __launch_bounds__(256) void gemm_proj(
    const unsigned short* __restrict__ Op0, const unsigned short* __restrict__ Op1,
    const float* __restrict__ lp0, const float* __restrict__ lp1,
    const unsigned short* __restrict__ Bt, const float* __restrict__ bias,
    const float* __restrict__ res, float* __restrict__ out) {
  constexpr int N = D_MODEL, K = D_MODEL;
  __shared__ __align__(16) unsigned short lsA[128 * 64];
  __shared__ __align__(16) unsigned short lsB[64 * 64];
  int tid = threadIdx.x;
  int lane = tid & 63, w = tid >> 6, quad = lane >> 4, l16 = lane & 15;
  int m0 = blockIdx.y * 128, n0 = blockIdx.x * 64;
  int wm = (w >> 1) * 64, wn = (w & 1) * 32;
  f4v acc[4][2] = {};
  for (int kt = 0; kt < K; kt += 64) {
    int h = kt >> 6;  // head index of this k-slab
    // A staging: combine Op0+Op1, scale by 1/(l0+l1), bf16 -> LDS (swizzled)
#pragma unroll
    for (int i = 0; i < 4; ++i) {
      int ci = tid + i * 256;
      int row = ci >> 3, c = ci & 7;
      int cs = c ^ (row & 7);
      int rowg = m0 + row;
      int bh = (rowg >> 11) * NH + h;
      int l = rowg & 2047;
      size_t lidx = (size_t)bh * SEQ + l;
      float inv = 1.f / (lp0[lidx] + lp1[lidx]);
      const unsigned short* a0 = Op0 + (size_t)rowg * D_MODEL + kt + cs * 8;
      const unsigned short* a1 = Op1 + (size_t)rowg * D_MODEL + kt + cs * 8;
      s8v v0 = *(const s8v*)a0;
      s8v v1 = *(const s8v*)a1;
      s8v av;
#pragma unroll
      for (int j = 0; j < 8; ++j)
        av[j] = (short)f2b((b2f((unsigned short)v0[j]) +
                            b2f((unsigned short)v1[j])) * inv);
      *(s8v*)(&lsA[ci * 8]) = av;
    }
    // B staging: async16
#pragma unroll
    for (int i = 0; i < 2; ++i) {
      int cb = w * 128 + i * 64;
      int ci = cb + lane;
      int row = ci >> 3, c = ci & 7;
      int cs = c ^ (row & 7);
      async16(Bt + (size_t)(n0 + row) * K + kt + cs * 8, &lsB[cb * 8]);
    }
    __builtin_amdgcn_s_waitcnt(0x0f70);  // vmcnt(0)
    __syncthreads();
#pragma unroll
    for (int s = 0; s < 2; ++s) {
      s8v af[4], bf[2];
#pragma unroll
      for (int t = 0; t < 4; ++t) {
        int am = wm + t * 16 + l16;
        int ac = (s * 4 + quad) ^ (am & 7);
        af[t] = *(const s8v*)(&lsA[am * 64 + ac * 8]);
      }
#pragma unroll
      for (int t = 0; t < 2; ++t) {
        int bn = wn + t * 16 + l16;
        int bc = (s * 4 + quad) ^ (bn & 7);
        bf[t] = *(const s8v*)(&lsB[bn * 64 + bc * 8]);
      }
#pragma unroll
      for (int ti = 0; ti < 4; ++ti)
#pragma unroll
        for (int tj = 0; tj < 2; ++tj)
          acc[ti][tj] = __builtin_amdgcn_mfma_f32_16x16x32_bf16(
              af[ti], bf[tj], acc[ti][tj], 0, 0, 0);
    }
    __syncthreads();
  }
#pragma unroll
  for (int tj = 0; tj < 2; ++tj) {
    int col = n0 + wn + tj * 16 + l16;
    float bv = bias[col];
#pragma unroll
    for (int ti = 0; ti < 4; ++ti) {
#pragma unroll
      for (int r = 0; r < 4; ++r) {
        int rowg = m0 + wm + ti * 16 + quad * 4 + r;
        out[(size_t)rowg * N + col] =
            acc[ti][tj][r] + bv + res[(size_t)rowg * N + col];
      }
    }
  }
}

// ---------------- fused flash attention (one key-split per dispatch) --------
// grid (bh=32, qb=16); block 256 = 4 waves; wave handles 32 q-rows.
// id%8 = bh%8 -> 4 heads/XCD, ~1MB working set per XCD L2.
// S^T = mfma(K,Q): exp'd C-frag IS a K=16 A-operand (register P).
__global__ __launch_bounds__(256) void flash_k(
    const unsigned short* __restrict__ kh, const unsigned short* __restrict__ khT,
    unsigned short* __restrict__ Op, float* __restrict__ lp, int split) {
  __shared__ __align__(16) unsigned short lsK[128 * 64];
  __shared__ __align__(16) unsigned short lsKT[64 * 128];
  int tid = threadIdx.x;
  int lane = tid & 63, w = tid >> 6, quad = lane >> 4, l16 = lane & 15;
  int bh = blockIdx.x, qb = blockIdx.y;
  const unsigned short* khB = kh + (size_t)bh * SEQ * DH;
  const unsigned short* khTB = khT + (size_t)bh * DH * SEQ;
  s8v aQ[2][2];
#pragma unroll
  for (int g = 0; g < 2; ++g) {
    int q = qb * 128 + w * 32 + g * 16 + l16;
#pragma unroll
    for (int s = 0; s < 2; ++s)
      aQ[g][s] = *(const s8v*)(khB + (size_t)q * DH + s * 32 + quad * 8);
  }
  float l_lane[2] = {0.f, 0.f};
  f4v accO[2][4] = {};
  const float kexp = 0.18033688f;  // 0.125 * log2(e)

  for (int kt8 = 0; kt8 < 8; ++kt8) {
    int key0 = split * 1024 + kt8 * 128;
#pragma unroll
    for (int i = 0; i < 4; ++i) {
      int cb = w * 256 + i * 64;
      int ci = cb + lane;
      int row = ci >> 3, c = ci & 7;
      int cs = c ^ (row & 7);
      async16(khB + (size_t)(key0 + row) * DH + cs * 8, &lsK[cb * 8]);
    }
#pragma unroll
    for (int i = 0; i < 4; ++i) {
      int cb = w * 256 + i * 64;
      int ci = cb + lane;
      int row = ci >> 4, c = ci & 15;
      int cs = c ^ (row & 15);
      async16(khTB + (size_t)row * SEQ + key0 + cs * 8, &lsKT[cb * 8]);
    }
    __builtin_amdgcn_s_waitcnt(0x0f70);  // vmcnt(0)
    __syncthreads();
#pragma unroll
    for (int half = 0; half < 2; ++half) {
      f4v accST[2][4] = {};
#pragma unroll
      for (int s = 0; s < 2; ++s) {
#pragma unroll
        for (int tj = 0; tj < 4; ++tj) {
          int key = half * 64 + tj * 16 + l16;
          int c = (s * 4 + quad) ^ (key & 7);
          s8v kf = *(const s8v*)(&lsK[key * 64 + c * 8]);
#pragma unroll
          for (int g = 0; g < 2; ++g)
            accST[g][tj] = __builtin_amdgcn_mfma_f32_16x16x32_bf16(
                kf, aQ[g][s], accST[g][tj], 0, 0, 0);
        }
      }
#pragma unroll
      for (int tj = 0; tj < 4; ++tj) {
        s4v pf[2];
#pragma unroll
        for (int g = 0; g < 2; ++g) {
#pragma unroll
          for (int r = 0; r < 4; ++r) {
            float p = exp2f(accST[g][tj][r] * kexp);
            l_lane[g] += p;
            unsigned int pb = __builtin_bit_cast(unsigned int, p * 1.00195312f);
            pf[g][r] = (short)(pb >> 16);
          }
        }
#pragma unroll
        for (int db = 0; db < 4; ++db) {
          int d = db * 16 + l16;
          int ch = (half * 8 + tj * 2 + (quad >> 1)) ^ (d & 15);
          s4v vf = *(const s4v*)(&lsKT[d * 128 + ch * 8 + (quad & 1) * 4]);
#pragma unroll
          for (int g = 0; g < 2; ++g)
            accO[g][db] = mfma16(pf[g], vf, accO[g][db]);
        }
      }
    }
    __syncthreads();
  }
  int b = bh >> 4, h = bh & 15;
#pragma unroll
  for (int g = 0; g < 2; ++g) {
    float lv = l_lane[g];
    lv += __shfl_xor(lv, 16, 64);
    lv += __shfl_xor(lv, 32, 64);
    if (quad == 0) {
      int q = qb * 128 + w * 32 + g * 16 + l16;
      lp[(size_t)bh * SEQ + q] = lv;
    }
#pragma unroll
    for (int r = 0; r < 4; ++r) {
      int l = qb * 128 + w * 32 + g * 16 + quad * 4 + r;
#pragma unroll
      for (int db = 0; db < 4; ++db) {
        int d = db * 16 + l16;
        Op[((size_t)(b * SEQ + l)) * D_MODEL + h * DH + d] = f2b(accO[g][db][r]);
      }
    }
  }
}

// ---------------- FC2 epilogue: out = x1 + S0 + S1 + bias -------------------
__global__ __launch_bounds__(256) void fuse_out(
    const float* __restrict__ x1, const float* __restrict__ S0,
    float* __restrict__ dout, const float* __restrict__ b2) {
  size_t base = (size_t)blockIdx.x * 1024 + threadIdx.x * 4;
  int c0 = (int)(base & 1023);
  float4 a = *(const float4*)(x1 + base);
  float4 b = *(const float4*)(S0 + base);
  float4 c = *(const float4*)(dout + base);
  float4 o;
  o.x = a.x + b.x + c.x + b2[c0];
  o.y = a.y + b.y + c.y + b2[c0 + 1];
  o.z = a.z + b.z + c.z + b2[c0 + 2];
  o.w = a.w + b.w + c.w + b2[c0 + 3];
  *(float4*)(dout + base) = o;
}

// ---------------------------------------------------------------------------
extern "C" void kernel_launch(void* const* d_in, const int* in_sizes, int n_in,
                              void* d_out, int out_size, void* d_ws, size_t ws_size,
                              hipStream_t stream) {
  (void)in_sizes; (void)n_in; (void)out_size;
  const float* x      = (const float*)d_in[0];
  const float* w_attn = (const float*)d_in[1];
  const float* b_attn = (const float*)d_in[2];
  const float* w_proj = (const float*)d_in[3];
  const float* b_proj = (const float*)d_in[4];
  const float* ln1_g  = (const float*)d_in[5];
  const float* ln1_b  = (const float*)d_in[6];
  const float* ln2_g  = (const float*)d_in[7];
  const float* ln2_b  = (const float*)d_in[8];
  const float* w_fc1  = (const float*)d_in[9];
  const float* b_fc1  = (const float*)d_in[10];
  const float* w_fc2  = (const float*)d_in[11];
  const float* b_fc2  = (const float*)d_in[12];

  char* ws = (char*)d_ws;
  float*          x1   = (float*)(ws);                                // 16MB
  unsigned short* hbuf = (unsigned short*)(ws + (size_t)(16u << 20)); // 8MB
  unsigned short* wT1  = (unsigned short*)(ws + (size_t)(24u << 20)); // 8MB
  unsigned short* wT2  = (unsigned short*)(ws + (size_t)(32u << 20)); // 8MB
  unsigned short* kh   = (unsigned short*)(ws + (size_t)(40u << 20)); // 8MB
  unsigned short* khT  = (unsigned short*)(ws + (size_t)(48u << 20)); // 8MB
  unsigned short* Op0  = hbuf;                                 // flash partials
  unsigned short* Op1  = wT1;
  float*          lp0  = (float*)(ws + (size_t)(32u << 20));   // 256KB
  float*          lp1  = lp0 + (size_t)BATCH * NH * SEQ;       // 256KB
  unsigned short* wTp  = kh;            // w_proj^T after kh dies
  unsigned short* fc1o = kh;            // [40,72M) unchunked / [40,56M) chunked
  float*          S0   = (float*)hbuf;  // FC2 split-0 partial (16MB, [16,32M))
  float* outf = (float*)d_out;
  bool big_ws = ws_size >= ((size_t)72u << 20);

  dim3 blk(256);
  // 1. h1 = LN1(x)
  hipLaunchKernelGGL(ln_kernel, dim3(MROWS), blk, 0, stream, x, ln1_g, ln1_b, hbuf);
  // 2. wT1 = (w_attn[:, 1024:2048])^T
  hipLaunchKernelGGL(transpose_b<float>, dim3(16, 16, 1), blk, 0, stream,
                     w_attn + 1024, wT1, 3 * D_MODEL, D_MODEL, 0LL, 0LL);
  // 3. kh[b,h,l,d] = h1 @ w_k + b_k
  hipLaunchKernelGGL((gemm_bt<0, false, true, 0, 64, true>), dim3(16, 32), blk, 0,
                     stream, hbuf, wT1, b_attn + 1024, nullptr, (void*)kh,
                     MROWS, D_MODEL, D_MODEL, D_MODEL, D_MODEL);
  // 4. khT[b,h,d,l]
  hipLaunchKernelGGL(transpose_b<unsigned short>, dim3(1, 32, 32), blk, 0, stream,
                     kh, khT, DH, SEQ, (long long)(SEQ * DH), (long long)(DH * SEQ));
  // 5. flash, one dispatch per key-split (overwrites hbuf/wT1 with partials)
  hipLaunchKernelGGL(flash_k, dim3(32, SEQ / 128), blk, 0, stream,
                     kh, khT, Op0, lp0, 0);
  hipLaunchKernelGGL(flash_k, dim3(32, SEQ / 128), blk, 0, stream,
                     kh, khT, Op1, lp1, 1);
  // 6. wTp = w_proj^T (kh region, dead after flash)
  hipLaunchKernelGGL(transpose_b<float>, dim3(16, 16, 1), blk, 0, stream,
                     w_proj, wTp, D_MODEL, D_MODEL, 0LL, 0LL);
  // 7. x1 = x + combine(Op0,Op1,l) @ w_proj + b_proj   (fused combine)
  hipLaunchKernelGGL(gemm_proj, dim3(16, 32), blk, 0, stream,
                     Op0, Op1, lp0, lp1, wTp, b_proj, x, x1);
  // 8. h2 = LN2(x1) -> hbuf (Op0 dead)
  hipLaunchKernelGGL(ln_kernel, dim3(MROWS), blk, 0, stream, x1, ln2_g, ln2_b, hbuf);
  // 9. wT1 = w_fc1^T (Op1 dead) ; wT2 = w_fc2^T (lpart consumed)
  hipLaunchKernelGGL(transpose_b<float>, dim3(64, 16, 1), blk, 0, stream,
                     w_fc1, wT1, 4 * D_MODEL, D_MODEL, 0LL, 0LL);
  hipLaunchKernelGGL(transpose_b<float>, dim3(16, 64, 1), blk, 0, stream,
                     w_fc2, wT2, D_MODEL, 4 * D_MODEL, 0LL, 0LL);
  if (big_ws) {
    // 10. fc1o = relu(h2 @ w_fc1 + b_fc1)   (BN=128, 1024 blocks)
    hipLaunchKernelGGL((gemm_bt<0, true, false, 0, 128, true>), dim3(32, 32), blk, 0,
                       stream, hbuf, wT1, b_fc1, nullptr, (void*)fc1o,
                       MROWS, 4 * D_MODEL, D_MODEL, D_MODEL, D_MODEL);
    // 11. FC2 split-K x2 (BN=128, 256 blocks each): S0 and d_out raw partials
    hipLaunchKernelGGL((gemm_bt<0, false, false, 1, 128, false>), dim3(8, 32), blk, 0,
                       stream, fc1o, wT2, nullptr, nullptr, (void*)S0,
                       MROWS, D_MODEL, 2 * D_MODEL, 4 * D_MODEL, 4 * D_MODEL);
    hipLaunchKernelGGL((gemm_bt<0, false, false, 1, 128, false>), dim3(8, 32), blk, 0,
                       stream, fc1o + 2 * D_MODEL, wT2 + 2 * D_MODEL, nullptr,
                       nullptr, (void*)outf,
                       MROWS, D_MODEL, 2 * D_MODEL, 4 * D_MODEL, 4 * D_MODEL);
    // 12. out = x1 + S0 + S1 + b_fc2
    hipLaunchKernelGGL(fuse_out, dim3(MROWS), blk, 0, stream, x1, S0, outf, b_fc2);
  } else {
    for (int c = 0; c < 2; ++c) {
      const unsigned short* h2c = hbuf + (size_t)c * 2048 * D_MODEL;
      const float* x1c = x1 + (size_t)c * 2048 * D_MODEL;
      float* outc = outf + (size_t)c * 2048 * D_MODEL;
      hipLaunchKernelGGL((gemm_bt<0, true, false, 0, 128, true>), dim3(32, 16), blk,
                         0, stream, h2c, wT1, b_fc1, nullptr, (void*)fc1o,
                         2048, 4 * D_MODEL, D_MODEL, D_MODEL, D_MODEL);
      hipLaunchKernelGGL((gemm_bt<2, false, false, 1, 64, true>), dim3(16, 16), blk,
                         0, stream, fc1o, wT2, b_fc2, x1c, (void*)outc,
                         2048, D_MODEL, 4 * D_MODEL, 4 * D_MODEL, 4 * D_MODEL);
    }
  }
}